// Round 2
// baseline (426.542 us; speedup 1.0000x reference)
//
#include <hip/hip_runtime.h>

// Bilinear scatter-add, v7.
// v6 post-mortem: accum was LATENCY-bound (29% occupancy, VALUBusy 17%,
// HBM 16%): 704 blocks x 4 waves = 2.75 blocks/CU, and 50 barriers/block
// with ~22 scattered row-loads between each. Fill residual ~barely moved
// despite 4x fewer atomics -> suspect the atomic-with-return path itself.
//
// v7 accum: 4x4 tile (keeps the 1.56x traffic factor), 512 thr = 8 waves,
// NO main-loop barriers: wave w owns entries e%8==w of every halo bin.
// Entry loads are wave-uniform broadcasts; feature rows load as float2
// (56 lanes, 448B coalesced). launch_bounds(512,6) -> 3 blocks/CU = 24
// waves/CU, ~48 rows in flight/CU (need ~20 to hide 900cy HBM latency).
// Cross-wave merge: 2-copy LDS tree, 4 barriers, epilogue only.
// v7 fill: 2 sub-buckets/bin keyed by p&1 (halves same-address atomic
// serialization) + 2 points/thread (2 independent RMWs in flight).

#define D     112
#define D2    56            // float2 per feature row
#define H     64
#define W     176
#define HW    (H * W)       // 11264
#define S     2             // sub-buckets per bin
#define SCAP  64            // per sub-bucket: mean 22.7, +8.7 sigma
#define CSTR  16            // counter stride in ints = 64B line
#define TY    4
#define TX    4
#define GX    (W / TX)      // 44
#define GY    (H / TY)      // 16
#define NCELL (TY * TX)     // 16
#define NW    8             // waves per accum block

__device__ __forceinline__ void fill_one(int p, float x, float y,
                                         int* cnt, uint2* bucket)
{
    float xf = floorf(x), yf = floorf(y);
    float wx = x - xf,    wy = y - yf;
    int x0 = min(max((int)xf, 0), W - 1);
    int y0 = min(max((int)yf, 0), H - 1);
    int sb = (y0 * W + x0) * S + (p & 1);
    unsigned qw = (__float2uint_rn(wy * 65535.0f) << 16)
                |  __float2uint_rn(wx * 65535.0f);
    int i = atomicAdd(&cnt[sb * CSTR], 1);
    if (i < SCAP) bucket[(size_t)sb * SCAP + i] = make_uint2((unsigned)p, qw);
}

__global__ __launch_bounds__(256) void fill_kernel(
    const float4* __restrict__ pos2,  // [N/2] packed (x0,y0,x1,y1)
    int* __restrict__ cnt,            // [HW*S*CSTR], pre-zeroed
    uint2* __restrict__ bucket,       // [HW*S*SCAP]
    int N)
{
    int i = blockIdx.x * blockDim.x + threadIdx.x;
    int p0 = 2 * i;
    if (p0 >= N) return;
    if (p0 + 1 < N) {
        float4 q = pos2[i];
        fill_one(p0,     q.x, q.y, cnt, bucket);
        fill_one(p0 + 1, q.z, q.w, cnt, bucket);
    } else {
        float2 q = ((const float2*)pos2)[p0];
        fill_one(p0, q.x, q.y, cnt, bucket);
    }
}

// One block per 4x4 cell tile; halo = 5x5 bins. A point in bin (gby,gbx)
// with weights (wx,wy) contributes (dy?wy:1-wy)*(dx?wx:1-wx)*feat[p] to
// cell (gby+dy,gbx+dx). Bin loops fully unrolled -> acc indices static.
__global__ __launch_bounds__(512, 6) void accum_kernel(
    const float* __restrict__ feat,      // [N, D]
    const int* __restrict__ cnt,
    const uint2* __restrict__ bucket,
    float* __restrict__ out)             // [H*W, D]
{
    const int tile = blockIdx.x;
    const int ty0  = (tile / GX) * TY;
    const int tx0  = (tile % GX) * TX;
    const int t    = threadIdx.x;
    const int wid  = t >> 6;
    const int lane = t & 63;
    const bool act = lane < D2;

    float2 acc[NCELL];
#pragma unroll
    for (int c = 0; c < NCELL; ++c) acc[c] = make_float2(0.0f, 0.0f);

#pragma unroll
    for (int by = -1; by < TY; ++by) {
#pragma unroll
        for (int bx = -1; bx < TX; ++bx) {
            const int gby = ty0 + by;
            const int gbx = tx0 + bx;
            if (gby < 0 || gbx < 0 || gbx >= W) continue;  // uniform
            const int bin = gby * W + gbx;
#pragma unroll
            for (int s = 0; s < S; ++s) {
                const int sb = bin * S + s;
                const int n  = min(cnt[sb * CSTR], SCAP);
                const uint2* __restrict__ bk = bucket + (size_t)sb * SCAP;
#pragma unroll 2
                for (int e = wid; e < n; e += NW) {
                    uint2 en = bk[e];               // wave-uniform broadcast
                    float wx = (float)(en.y & 0xffffu) * (1.0f / 65535.0f);
                    float wy = (float)(en.y >> 16)     * (1.0f / 65535.0f);
                    float2 f = make_float2(0.0f, 0.0f);
                    if (act)
                        f = ((const float2*)(feat + (size_t)en.x * D))[lane];
                    float ax = 1.0f - wx, ay = 1.0f - wy;
#pragma unroll
                    for (int dy = 0; dy < 2; ++dy) {
                        const int cy = by + dy;          // compile-time
                        if (cy < 0 || cy >= TY) continue;
                        const float fy = dy ? wy : ay;
#pragma unroll
                        for (int dx = 0; dx < 2; ++dx) {
                            const int cx = bx + dx;      // compile-time
                            if (cx < 0 || cx >= TX) continue;
                            const float fw = fy * (dx ? wx : ax);
                            const int c = cy * TX + cx;
                            acc[c].x = fmaf(fw, f.x, acc[c].x);
                            acc[c].y = fmaf(fw, f.y, acc[c].y);
                        }
                    }
                }
            }
        }
    }

    // Cross-wave merge: waves 0-3 -> copy 0, waves 4-7 -> copy 1 (parallel
    // halves, serial depth 4), then combine the two copies at store.
    __shared__ float2 sacc[2][NCELL][D2];
    const int half = wid >> 2;
    const int sub  = wid & 3;

    for (int w = 0; w < 4; ++w) {
        if (sub == w && act) {
            if (w == 0) {
#pragma unroll
                for (int c = 0; c < NCELL; ++c) sacc[half][c][lane] = acc[c];
            } else {
#pragma unroll
                for (int c = 0; c < NCELL; ++c) {
                    float2 v = sacc[half][c][lane];
                    v.x += acc[c].x; v.y += acc[c].y;
                    sacc[half][c][lane] = v;
                }
            }
        }
        __syncthreads();
    }

    // store: wave w stores cells 2w and 2w+1; 448B coalesced per cell
    if (act) {
#pragma unroll
        for (int k = 0; k < 2; ++k) {
            const int c  = wid * 2 + k;
            const int cy = c / TX, cx = c % TX;
            float2 v0 = sacc[0][c][lane];
            float2 v1 = sacc[1][c][lane];
            float2* dst = (float2*)(out + ((size_t)(ty0 + cy) * W + (tx0 + cx)) * D);
            dst[lane] = make_float2(v0.x + v1.x, v0.y + v1.y);
        }
    }
}

extern "C" void kernel_launch(void* const* d_in, const int* in_sizes, int n_in,
                              void* d_out, int out_size, void* d_ws, size_t ws_size,
                              hipStream_t stream) {
    const float4* pos2 = (const float4*)d_in[0];
    const float* feat  = (const float*)d_in[1];
    float* out         = (float*)d_out;

    const int N = in_sizes[0] / 2;

    int* cnt      = (int*)d_ws;
    uint2* bucket = (uint2*)((char*)d_ws + (size_t)HW * S * CSTR * sizeof(int));
    // ws use: 11264*2*16*4 B (1.44 MB) + 11264*2*64*8 B (11.5 MB) = 13.0 MB

    hipMemsetAsync(cnt, 0, (size_t)HW * S * CSTR * sizeof(int), stream);

    int npair = (N + 1) / 2;
    fill_kernel<<<(npair + 255) / 256, 256, 0, stream>>>(pos2, cnt, bucket, N);

    accum_kernel<<<GY * GX, 512, 0, stream>>>(feat, cnt, bucket, out);
}

// Round 3
// 364.089 us; speedup vs baseline: 1.1715x; 1.1715x over previous
//
#include <hip/hip_runtime.h>

// Bilinear scatter-add, v8.
// v7 post-mortem: accum REGRESSED 156->177us (HBM 14.7%, VALU 12.7%): the
// e%8 wave-split gave each wave ~2.8 entries per sub-bucket across 50
// sub-buckets -> per-wave stream dominated by dependent cnt loads + tiny
// loops + 8x duplicated header reads; only ~2 rows in flight per wave.
// Also: top-5 (sorted by dur) shows only accum -> fill < 148us in r0, and
// the 3-round system solves to ~186us fixed overhead + fill ~60us.
// Sub-buckets bought nothing -> same-address atomics were never the fill
// bottleneck; reverted (S=1).
//
// v8 accum: same 4x4 tile (keeps FETCH ~197MB), but wave w owns WHOLE bins
// (binLin%8==w, compile-time in the unrolled 5x5 loop -> acc indices stay
// static). Each wave streams 130-180 entries from its 3-4 bins with manual
// 4-entry batching: 4 header loads, then 4 independent 448B row loads in
// flight, then FMAs. No barriers until the epilogue merge. 22 waves/CU x 4
// rows >= 88 concurrent rows/CU >> ~20 needed to cover HBM latency.

#define D     112
#define D2    56            // float2 per feature row
#define H     64
#define W     176
#define HW    (H * W)       // 11264
#define CAP   128           // mean 45.4/bin, sigma 6.7 -> +12 sigma
#define CSTR  16            // counter stride in ints = 64B line
#define TY    4
#define TX    4
#define GX    (W / TX)      // 44
#define GY    (H / TY)      // 16
#define NCELL (TY * TX)     // 16
#define NW    8             // waves per accum block

__device__ __forceinline__ void fill_one(int p, float x, float y,
                                         int* cnt, uint2* bucket)
{
    float xf = floorf(x), yf = floorf(y);
    float wx = x - xf,    wy = y - yf;
    int x0 = min(max((int)xf, 0), W - 1);
    int y0 = min(max((int)yf, 0), H - 1);
    int bin = y0 * W + x0;
    unsigned qw = (__float2uint_rn(wy * 65535.0f) << 16)
                |  __float2uint_rn(wx * 65535.0f);
    int i = atomicAdd(&cnt[bin * CSTR], 1);
    if (i < CAP) bucket[(size_t)bin * CAP + i] = make_uint2((unsigned)p, qw);
}

__global__ __launch_bounds__(256) void fill_kernel(
    const float4* __restrict__ pos2,  // [N/2] packed (x0,y0,x1,y1)
    int* __restrict__ cnt,            // [HW*CSTR], pre-zeroed
    uint2* __restrict__ bucket,       // [HW*CAP]
    int N)
{
    int i = blockIdx.x * blockDim.x + threadIdx.x;
    int p0 = 2 * i;
    if (p0 >= N) return;
    if (p0 + 1 < N) {
        float4 q = pos2[i];
        fill_one(p0,     q.x, q.y, cnt, bucket);
        fill_one(p0 + 1, q.z, q.w, cnt, bucket);
    } else {
        float2 q = ((const float2*)pos2)[p0];
        fill_one(p0, q.x, q.y, cnt, bucket);
    }
}

// One block per 4x4 cell tile; halo = 5x5 bins. A point in bin (gby,gbx)
// with weights (wx,wy) contributes (dy?wy:1-wy)*(dx?wx:1-wx)*feat[p] to
// cell (gby+dy,gbx+dx). Bin loops fully unrolled -> acc indices static.
__global__ __launch_bounds__(512, 6) void accum_kernel(
    const float* __restrict__ feat,      // [N, D]
    const int* __restrict__ cnt,
    const uint2* __restrict__ bucket,
    float* __restrict__ out)             // [H*W, D]
{
    const int tile = blockIdx.x;
    const int ty0  = (tile / GX) * TY;
    const int tx0  = (tile % GX) * TX;
    const int t    = threadIdx.x;
    const int wid  = t >> 6;
    const int lane = t & 63;
    const bool act = lane < D2;

    float2 acc[NCELL];
#pragma unroll
    for (int c = 0; c < NCELL; ++c) acc[c] = make_float2(0.0f, 0.0f);

#pragma unroll
    for (int by = -1; by < TY; ++by) {
#pragma unroll
        for (int bx = -1; bx < TX; ++bx) {
            const int binLin = (by + 1) * 5 + (bx + 1);   // 0..24, compile-time
            if ((binLin & 7) != wid) continue;            // wave-uniform skip
            const int gby = ty0 + by;
            const int gbx = tx0 + bx;
            if (gby < 0 || gbx < 0 || gbx >= W) continue; // uniform

            const int n = min(cnt[(gby * W + gbx) * CSTR], CAP);
            const uint2* __restrict__ bk =
                bucket + (size_t)(gby * W + gbx) * CAP;

            // one entry's contribution; by/bx are compile-time constants
            auto proc = [&](uint2 en, float2 f) {
                float wx = (float)(en.y & 0xffffu) * (1.0f / 65535.0f);
                float wy = (float)(en.y >> 16)     * (1.0f / 65535.0f);
                float ax = 1.0f - wx, ay = 1.0f - wy;
#pragma unroll
                for (int dy = 0; dy < 2; ++dy) {
                    const int cy = by + dy;
                    if (cy < 0 || cy >= TY) continue;
                    const float fy = dy ? wy : ay;
#pragma unroll
                    for (int dx = 0; dx < 2; ++dx) {
                        const int cx = bx + dx;
                        if (cx < 0 || cx >= TX) continue;
                        const float fw = fy * (dx ? wx : ax);
                        const int c = cy * TX + cx;
                        acc[c].x = fmaf(fw, f.x, acc[c].x);
                        acc[c].y = fmaf(fw, f.y, acc[c].y);
                    }
                }
            };
            auto ldrow = [&](unsigned p) -> float2 {
                return act ? ((const float2*)(feat + (size_t)p * D))[lane]
                           : make_float2(0.0f, 0.0f);
            };

            int e = 0;
            for (; e + 4 <= n; e += 4) {     // 4 rows in flight per wave
                uint2 n0 = bk[e], n1 = bk[e + 1], n2 = bk[e + 2], n3 = bk[e + 3];
                float2 f0 = ldrow(n0.x);
                float2 f1 = ldrow(n1.x);
                float2 f2 = ldrow(n2.x);
                float2 f3 = ldrow(n3.x);
                proc(n0, f0); proc(n1, f1); proc(n2, f2); proc(n3, f3);
            }
            for (; e < n; ++e) {
                uint2 n0 = bk[e];
                proc(n0, ldrow(n0.x));
            }
        }
    }

    // Cross-wave merge: waves 0-3 -> copy 0, waves 4-7 -> copy 1 (parallel
    // halves, serial depth 4), then combine the two copies at store.
    __shared__ float2 sacc[2][NCELL][D2];
    const int half = wid >> 2;
    const int sub  = wid & 3;

    for (int w = 0; w < 4; ++w) {
        if (sub == w && act) {
            if (w == 0) {
#pragma unroll
                for (int c = 0; c < NCELL; ++c) sacc[half][c][lane] = acc[c];
            } else {
#pragma unroll
                for (int c = 0; c < NCELL; ++c) {
                    float2 v = sacc[half][c][lane];
                    v.x += acc[c].x; v.y += acc[c].y;
                    sacc[half][c][lane] = v;
                }
            }
        }
        __syncthreads();
    }

    // store: wave w stores cells 2w and 2w+1; 448B coalesced per cell
    if (act) {
#pragma unroll
        for (int k = 0; k < 2; ++k) {
            const int c  = wid * 2 + k;
            const int cy = c / TX, cx = c % TX;
            float2 v0 = sacc[0][c][lane];
            float2 v1 = sacc[1][c][lane];
            float2* dst = (float2*)(out + ((size_t)(ty0 + cy) * W + (tx0 + cx)) * D);
            dst[lane] = make_float2(v0.x + v1.x, v0.y + v1.y);
        }
    }
}

extern "C" void kernel_launch(void* const* d_in, const int* in_sizes, int n_in,
                              void* d_out, int out_size, void* d_ws, size_t ws_size,
                              hipStream_t stream) {
    const float4* pos2 = (const float4*)d_in[0];
    const float* feat  = (const float*)d_in[1];
    float* out         = (float*)d_out;

    const int N = in_sizes[0] / 2;

    int* cnt      = (int*)d_ws;
    uint2* bucket = (uint2*)((char*)d_ws + (size_t)HW * CSTR * sizeof(int));
    // ws use: 11264*16*4 B (720 KB) + 11264*128*8 B (11.5 MB) = 12.2 MB

    hipMemsetAsync(cnt, 0, (size_t)HW * CSTR * sizeof(int), stream);

    int npair = (N + 1) / 2;
    fill_kernel<<<(npair + 255) / 256, 256, 0, stream>>>(pos2, cnt, bucket, N);

    accum_kernel<<<GY * GX, 512, 0, stream>>>(feat, cnt, bucket, out);
}